// Round 13
// baseline (588.732 us; speedup 1.0000x reference)
//
#include <hip/hip_runtime.h>

// MultiHeadElman scan, R13: all-VALU critical path via overlapping-pair DPP.
// h_{t+1} = softsign(R@h + Wx@x_t + bias), T=4096, 256 chains, 1 wave each.
// Lane layout (q,g), R8-proven: q=l&15, g=l>>4;
//   g0: rows 0-15/j-lo  g1: rows 16-31/j-hi  g2: rows 0-15/j-hi  g3: 16-31/j-lo
// Step chain (NO LDS-pipe ops): permlane16 fix -> hd = h[joff+c] ->
//   pd = cvtpk(hd, DPP-next(hd)) -> 7x DPP ror:2d + 8x v_dot2_f32_f16
//   (overlapping-pair covers: starts {c+2d} mod 16 are a disjoint pair cover
//   for any c; odd lanes use the wrapped cover, weights pre-indexed) ->
//   permlane32 u+v combine -> softsign.
// wx via two mfma_f32_16x16x32_f16 per 16-step block + global_load_lds
// staging + counted vmcnt (all R12-proven, unchanged).

typedef __fp16 f16x2 __attribute__((ext_vector_type(2)));
typedef __fp16 f16x8 __attribute__((ext_vector_type(8)));
typedef float  f32x4 __attribute__((ext_vector_type(4)));
typedef unsigned int v2u __attribute__((ext_vector_type(2)));

constexpr int T_STEPS = 4096;
constexpr int B_SZ    = 4;
constexpr int D_SZ    = 2048;
constexpr int H_SZ    = 64;
constexpr int HD      = 32;
constexpr long ST     = (long)B_SZ * D_SZ;   // 8192 floats per t
constexpr int BLK     = 16;                  // steps per block

typedef const __attribute__((address_space(1))) void* gas_t;
typedef __attribute__((address_space(3))) void*       las_t;

#if __has_builtin(__builtin_amdgcn_fdot2)
__device__ __forceinline__ float FDOT2(f16x2 a, f16x2 b, float c) {
    return __builtin_amdgcn_fdot2(a, b, c, false);
}
#else
__device__ __forceinline__ float FDOT2(f16x2 a, f16x2 b, float c) {
    return fmaf((float)a.x, (float)b.x, fmaf((float)a.y, (float)b.y, c));
}
#endif

// pair-rotation: lane c receives the pair register of lane (c+2D)&15.
template<bool RM, int D>
__device__ __forceinline__ f16x2 rot2(unsigned u) {
    constexpr int ctrl = 0x120 + (RM ? (16 - 2 * D) : (2 * D));
    const unsigned r = (unsigned)__builtin_amdgcn_update_dpp(
        (int)u, (int)u, ctrl, 0xF, 0xF, false);
    return __builtin_bit_cast(f16x2, r);
}
// neighbor: lane c receives lane (c+1)&15's value.
template<bool RM>
__device__ __forceinline__ float nexth(float v) {
    constexpr int ctrl = 0x120 + (RM ? 15 : 1);
    return __int_as_float(__builtin_amdgcn_update_dpp(
        __float_as_int(v), __float_as_int(v), ctrl, 0xF, 0xF, false));
}

union AF { f16x8 v; f16x2 pcs[4]; };

struct Ctx {
    f16x2 w0, w1, w2, w3, w4, w5, w6, w7;   // wrapped-cover R pairs
    AF bf0, bf1;                            // MFMA B frags (0.5*Wx^T, f16)
    float bn0, bn1;                         // 0.5*bias C-init
    int aw0, aw1;                           // A-frag LDS word offsets
    int mr, nc;                             // C-tile write coords
    int row;
    bool sel_x, low32;
    const float* gx0; const float* gx1;     // gl_lds sources
    float* op;                              // ys stream pointer
    float* ofin;                            // h_final address
};

template<bool RM>
__device__ __forceinline__ void run_scan(Ctx cx, float hn,
                                         float (&xl)[2][512],
                                         float (&wxl)[2][BLK + 2][32])
{
#define STAGE(nbuf, t0) do {                                                  \
        __builtin_amdgcn_global_load_lds((gas_t)(cx.gx0 + (long)(t0) * ST),   \
                                         (las_t)&xl[nbuf][0],   16, 0, 0);    \
        __builtin_amdgcn_global_load_lds((gas_t)(cx.gx1 + (long)(t0) * ST),   \
                                         (las_t)&xl[nbuf][256], 16, 0, 0);    \
    } while (0)

#define COMPUTE_WX(nbuf) do {                                                 \
        float4 xa = *(const float4*)&xl[nbuf][cx.aw0];                        \
        float4 xc = *(const float4*)&xl[nbuf][cx.aw1];                        \
        AF af;                                                                \
        af.pcs[0] = __builtin_amdgcn_cvt_pkrtz(xa.x, xa.y);                   \
        af.pcs[1] = __builtin_amdgcn_cvt_pkrtz(xa.z, xa.w);                   \
        af.pcs[2] = __builtin_amdgcn_cvt_pkrtz(xc.x, xc.y);                   \
        af.pcs[3] = __builtin_amdgcn_cvt_pkrtz(xc.z, xc.w);                   \
        f32x4 c0 = {cx.bn0, cx.bn0, cx.bn0, cx.bn0};                          \
        f32x4 c1 = {cx.bn1, cx.bn1, cx.bn1, cx.bn1};                          \
        c0 = __builtin_amdgcn_mfma_f32_16x16x32_f16(af.v, cx.bf0.v, c0,       \
                                                    0, 0, 0);                 \
        c1 = __builtin_amdgcn_mfma_f32_16x16x32_f16(af.v, cx.bf1.v, c1,       \
                                                    0, 0, 0);                 \
        wxl[nbuf][cx.mr + 0][cx.nc] = c0[0];                                  \
        wxl[nbuf][cx.mr + 0][cx.nc + 16] = c1[0];                             \
        wxl[nbuf][cx.mr + 1][cx.nc] = c0[1];                                  \
        wxl[nbuf][cx.mr + 1][cx.nc + 16] = c1[1];                             \
        wxl[nbuf][cx.mr + 2][cx.nc] = c0[2];                                  \
        wxl[nbuf][cx.mr + 2][cx.nc + 16] = c1[2];                             \
        wxl[nbuf][cx.mr + 3][cx.nc] = c0[3];                                  \
        wxl[nbuf][cx.mr + 3][cx.nc + 16] = c1[3];                             \
    } while (0)

    // ---- prologue: block 0 ----
    STAGE(0, 0);
    asm volatile("s_waitcnt vmcnt(0)" ::: "memory");
    COMPUTE_WX(0);
    float wx0 = wxl[0][0][cx.row];     // this step's wx/2
    float wx1 = wxl[0][1][cx.row];     // next step's wx/2
    float* op = cx.op;

    for (int tb = 0; tb < T_STEPS; tb += BLK) {
        const int cur = (tb >> 4) & 1, nxt = cur ^ 1;
        const bool more = (tb + BLK) < T_STEPS;
        if (more) STAGE(nxt, tb + BLK);       // unsinkable gl_lds

#pragma clang loop unroll(disable)
        for (int k = 0; k < BLK; ++k) {
            const float wxn = wxl[cur][k + 2][cx.row];   // 2-ahead (pad rows)

            // dot-ready h: g0/g1 own, g2/g3 partner l^16 (probed select)
            const v2u hp = __builtin_amdgcn_permlane16_swap(
                __float_as_uint(hn), __float_as_uint(hn), false, false);
            const float from16 = __uint_as_float(cx.sel_x ? hp.x : hp.y);
            const float hd = cx.low32 ? hn : from16;     // = h[joff + c]

            // in-register pair: (h[joff+c], h[joff+c+1])
            const f16x2 pd = __builtin_amdgcn_cvt_pkrtz(hd, nexth<RM>(hd));
            const unsigned pdu = __builtin_bit_cast(unsigned, pd);

            // 8 fdot2 over the overlapping-pair cover {c+2d}
            float a0 = FDOT2(pd,               cx.w0, wx0);  // wx/2 folded in
            float a1 = FDOT2(rot2<RM, 1>(pdu), cx.w1, 0.0f);
            a0 = FDOT2(rot2<RM, 2>(pdu), cx.w2, a0);
            a1 = FDOT2(rot2<RM, 3>(pdu), cx.w3, a1);
            a0 = FDOT2(rot2<RM, 4>(pdu), cx.w4, a0);
            a1 = FDOT2(rot2<RM, 5>(pdu), cx.w5, a1);
            a0 = FDOT2(rot2<RM, 6>(pdu), cx.w6, a0);
            a1 = FDOT2(rot2<RM, 7>(pdu), cx.w7, a1);
            const float s = a0 + a1;

            // half-combine (R8-proven): {x,y} = {own, partner} either way
            const v2u sp = __builtin_amdgcn_permlane32_swap(
                __float_as_uint(s), __float_as_uint(s), false, false);
            const float pre = __uint_as_float(sp.x) + __uint_as_float(sp.y);

            // softsign
            hn = pre * __builtin_amdgcn_rcpf(1.0f + __builtin_fabsf(pre));

            op[0] = hn;            // dup lanes: same value, same address
            op += ST;
            wx0 = wx1; wx1 = wxn;
        }

        if (more) {
            // queue: [2 gl_lds][16 stores] -> vmcnt(16) = gl_lds drained
            asm volatile("s_waitcnt vmcnt(16)" ::: "memory");
            COMPUTE_WX(nxt);
            wx0 = wxl[nxt][0][cx.row];
            wx1 = wxl[nxt][1][cx.row];
        }
    }

    cx.ofin[0] = hn;               // h_final (duplicates identical)
#undef STAGE
#undef COMPUTE_WX
}

__global__ __launch_bounds__(64, 1)
void elman_fused(const float* __restrict__ x,
                 const float* __restrict__ h0,
                 const float* __restrict__ R,
                 const float* __restrict__ Wx,
                 const float* __restrict__ bias,
                 float* __restrict__ out)
{
    const int l = threadIdx.x & 63;
    const int c = l & 15;                // position within DPP row
    const int g = l >> 4;
    const int joff = (g == 1 || g == 2) ? 16 : 0;
    const int row  = (g & 1) ? 16 + c : c;
    const int h = blockIdx.x & (H_SZ - 1);
    const int b = blockIdx.x >> 6;

    // ---- convention probes (R8-proven) ----
    const int pr = __builtin_amdgcn_update_dpp(l, l, 0x121, 0xF, 0xF, false);
    const bool ror_minus = ((pr & 15) == ((c - 1) & 15));
    const v2u pp = __builtin_amdgcn_permlane16_swap((unsigned)l, (unsigned)l,
                                                    false, false);

    Ctx cx;
    cx.sel_x = (pp.x == (unsigned)(l ^ 16));
    cx.low32 = (l < 32);
    cx.row = row;

    // ---- wrapped-cover R weight pairs: start s_d = (c+2d)&15 ----
    {
        const float* Rrow = R + (h * HD + row) * HD + joff;
        f16x2 t[8];
#pragma unroll
        for (int d = 0; d < 8; ++d) {
            const int s = (c + 2 * d) & 15;
            t[d] = __builtin_amdgcn_cvt_pkrtz(Rrow[s], Rrow[(s + 1) & 15]);
        }
        cx.w0 = t[0]; cx.w1 = t[1]; cx.w2 = t[2]; cx.w3 = t[3];
        cx.w4 = t[4]; cx.w5 = t[5]; cx.w6 = t[6]; cx.w7 = t[7];
    }

    // ---- MFMA B fragments: B[k][n] = 0.5*Wx[h][n][k] f16 (R12-proven) ----
    {
        const int n  = l & 15;
        const int k0 = (l >> 4) * 8;
        const float4* wp0 = (const float4*)(Wx + (h * HD + n) * HD + k0);
        const float4* wp1 = (const float4*)(Wx + (h * HD + n + 16) * HD + k0);
        float4 u = wp0[0], v = wp0[1];
        cx.bf0.pcs[0] = __builtin_amdgcn_cvt_pkrtz(0.5f * u.x, 0.5f * u.y);
        cx.bf0.pcs[1] = __builtin_amdgcn_cvt_pkrtz(0.5f * u.z, 0.5f * u.w);
        cx.bf0.pcs[2] = __builtin_amdgcn_cvt_pkrtz(0.5f * v.x, 0.5f * v.y);
        cx.bf0.pcs[3] = __builtin_amdgcn_cvt_pkrtz(0.5f * v.z, 0.5f * v.w);
        u = wp1[0]; v = wp1[1];
        cx.bf1.pcs[0] = __builtin_amdgcn_cvt_pkrtz(0.5f * u.x, 0.5f * u.y);
        cx.bf1.pcs[1] = __builtin_amdgcn_cvt_pkrtz(0.5f * u.z, 0.5f * u.w);
        cx.bf1.pcs[2] = __builtin_amdgcn_cvt_pkrtz(0.5f * v.x, 0.5f * v.y);
        cx.bf1.pcs[3] = __builtin_amdgcn_cvt_pkrtz(0.5f * v.z, 0.5f * v.w);
        cx.bn0 = 0.5f * bias[h * HD + n];
        cx.bn1 = 0.5f * bias[h * HD + n + 16];
        cx.mr = (l >> 4) * 4;
        cx.nc = n;
    }

    // A-frag LDS word offsets (R10-proven)
    {
        const int J0 = (l >> 4) * 2, J1 = J0 + 1;
        cx.aw0 = 64 * (J0 & 3) + 4 * (l & 15) + 256 * (J0 >> 2);
        cx.aw1 = 64 * (J1 & 3) + 4 * (l & 15) + 256 * (J1 >> 2);
    }

    cx.gx0 = x + (long)(l & 15) * ST + (long)b * D_SZ + h * HD + (l >> 4) * 4;
    cx.gx1 = cx.gx0 + 16;
    cx.op  = out + (long)b * D_SZ + h * HD + row;
    cx.ofin = out + (long)T_STEPS * ST + (b * H_SZ + h) * HD + row;

    const float hn = h0[(b * H_SZ + h) * HD + row];

    __shared__ __align__(16) float xl[2][512];
    __shared__ float wxl[2][BLK + 2][32];

    if (ror_minus) run_scan<true>(cx, hn, xl, wxl);
    else           run_scan<false>(cx, hn, xl, wxl);
}

extern "C" void kernel_launch(void* const* d_in, const int* in_sizes, int n_in,
                              void* d_out, int out_size, void* d_ws, size_t ws_size,
                              hipStream_t stream) {
    const float* x    = (const float*)d_in[0];
    const float* h0   = (const float*)d_in[1];
    const float* R    = (const float*)d_in[2];
    const float* Wx   = (const float*)d_in[3];
    const float* bias = (const float*)d_in[4];
    float* out = (float*)d_out;

    elman_fused<<<dim3(B_SZ * H_SZ), dim3(64), 0, stream>>>(x, h0, R, Wx, bias, out);
}

// Round 14
// 524.022 us; speedup vs baseline: 1.1235x; 1.1235x over previous
//
#include <hip/hip_runtime.h>

// MultiHeadElman scan, R14 = R13 with wx moved fully into registers.
// Key change: wx LDS tile TRANSPOSED to wxT[32 rows][20 steps] so each lane
// fetches a 4-step QUAD of its own row's wx with one ds_read_b128, prefetched
// one 4-step group ahead (~300cy in flight >> 120cy LDS latency). This kills
// the per-step ds_read whose lgkm drain at the rolled-loop back-edge was the
// R12/R13 stall (~120cy/step exposed).
// Step math identical to R13 (proven): permlane16 fix -> pd=cvtpk(hd,next) ->
// 7x DPP ror:2d + 8x fdot2 over the overlapping-pair cover -> permlane32
// u+v combine -> softsign. wx/2 folded into a0 init; pre = u+v carries it.
// MFMA wx projection + global_load_lds staging + counted vmcnt: R10-proven.

typedef __fp16 f16x2 __attribute__((ext_vector_type(2)));
typedef __fp16 f16x8 __attribute__((ext_vector_type(8)));
typedef float  f32x4 __attribute__((ext_vector_type(4)));
typedef unsigned int v2u __attribute__((ext_vector_type(2)));

constexpr int T_STEPS = 4096;
constexpr int B_SZ    = 4;
constexpr int D_SZ    = 2048;
constexpr int H_SZ    = 64;
constexpr int HD      = 32;
constexpr long ST     = (long)B_SZ * D_SZ;   // 8192 floats per t
constexpr int BLK     = 16;                  // steps per block
constexpr int WPAD    = 20;                  // wxT row pitch (16B-aligned quads)

typedef const __attribute__((address_space(1))) void* gas_t;
typedef __attribute__((address_space(3))) void*       las_t;

#if __has_builtin(__builtin_amdgcn_fdot2)
__device__ __forceinline__ float FDOT2(f16x2 a, f16x2 b, float c) {
    return __builtin_amdgcn_fdot2(a, b, c, false);
}
#else
__device__ __forceinline__ float FDOT2(f16x2 a, f16x2 b, float c) {
    return fmaf((float)a.x, (float)b.x, fmaf((float)a.y, (float)b.y, c));
}
#endif

// pair-rotation: lane c receives the pair register of lane (c+2D)&15.
template<bool RM, int D>
__device__ __forceinline__ f16x2 rot2(unsigned u) {
    constexpr int ctrl = 0x120 + (RM ? (16 - 2 * D) : (2 * D));
    const unsigned r = (unsigned)__builtin_amdgcn_update_dpp(
        (int)u, (int)u, ctrl, 0xF, 0xF, false);
    return __builtin_bit_cast(f16x2, r);
}
// neighbor: lane c receives lane (c+1)&15's value.
template<bool RM>
__device__ __forceinline__ float nexth(float v) {
    constexpr int ctrl = 0x120 + (RM ? 15 : 1);
    return __int_as_float(__builtin_amdgcn_update_dpp(
        __float_as_int(v), __float_as_int(v), ctrl, 0xF, 0xF, false));
}

union AF { f16x8 v; f16x2 pcs[4]; };

struct Ctx {
    f16x2 w0, w1, w2, w3, w4, w5, w6, w7;   // wrapped-cover R pairs
    AF bf0, bf1;                            // MFMA B frags (0.5*Wx^T, f16)
    float bn0, bn1;                         // 0.5*bias C-init
    int aw0, aw1;                           // A-frag LDS word offsets
    int mr, nc;                             // C-tile write coords
    int row;
    bool sel_x, low32;
    const float* gx0; const float* gx1;     // gl_lds sources
    float* op;                              // ys stream pointer
    float* ofin;                            // h_final address
};

template<bool RM>
__device__ __forceinline__ void run_scan(Ctx cx, float hn,
                                         float (&xl)[2][512],
                                         float (&wxT)[2][32][WPAD])
{
#define STAGE(nbuf, t0) do {                                                  \
        __builtin_amdgcn_global_load_lds((gas_t)(cx.gx0 + (long)(t0) * ST),   \
                                         (las_t)&xl[nbuf][0],   16, 0, 0);    \
        __builtin_amdgcn_global_load_lds((gas_t)(cx.gx1 + (long)(t0) * ST),   \
                                         (las_t)&xl[nbuf][256], 16, 0, 0);    \
    } while (0)

#define COMPUTE_WX(nbuf) do {                                                 \
        float4 xa = *(const float4*)&xl[nbuf][cx.aw0];                        \
        float4 xc = *(const float4*)&xl[nbuf][cx.aw1];                        \
        AF af;                                                                \
        af.pcs[0] = __builtin_amdgcn_cvt_pkrtz(xa.x, xa.y);                   \
        af.pcs[1] = __builtin_amdgcn_cvt_pkrtz(xa.z, xa.w);                   \
        af.pcs[2] = __builtin_amdgcn_cvt_pkrtz(xc.x, xc.y);                   \
        af.pcs[3] = __builtin_amdgcn_cvt_pkrtz(xc.z, xc.w);                   \
        f32x4 c0 = {cx.bn0, cx.bn0, cx.bn0, cx.bn0};                          \
        f32x4 c1 = {cx.bn1, cx.bn1, cx.bn1, cx.bn1};                          \
        c0 = __builtin_amdgcn_mfma_f32_16x16x32_f16(af.v, cx.bf0.v, c0,       \
                                                    0, 0, 0);                 \
        c1 = __builtin_amdgcn_mfma_f32_16x16x32_f16(af.v, cx.bf1.v, c1,       \
                                                    0, 0, 0);                 \
        *(f32x4*)&wxT[nbuf][cx.nc][cx.mr]      = c0;                          \
        *(f32x4*)&wxT[nbuf][cx.nc + 16][cx.mr] = c1;                          \
    } while (0)

// one scan step; WXV = this step's wx/2 (register, quad component)
#define STEP(WXV) do {                                                        \
        const v2u hp = __builtin_amdgcn_permlane16_swap(                      \
            __float_as_uint(hn), __float_as_uint(hn), false, false);          \
        const float from16 = __uint_as_float(cx.sel_x ? hp.x : hp.y);         \
        const float hd = cx.low32 ? hn : from16;                              \
        const f16x2 pd = __builtin_amdgcn_cvt_pkrtz(hd, nexth<RM>(hd));       \
        const unsigned pdu = __builtin_bit_cast(unsigned, pd);                \
        float a0 = FDOT2(pd,               cx.w0, (WXV));                     \
        float a1 = FDOT2(rot2<RM, 1>(pdu), cx.w1, 0.0f);                      \
        a0 = FDOT2(rot2<RM, 2>(pdu), cx.w2, a0);                              \
        a1 = FDOT2(rot2<RM, 3>(pdu), cx.w3, a1);                              \
        a0 = FDOT2(rot2<RM, 4>(pdu), cx.w4, a0);                              \
        a1 = FDOT2(rot2<RM, 5>(pdu), cx.w5, a1);                              \
        a0 = FDOT2(rot2<RM, 6>(pdu), cx.w6, a0);                              \
        a1 = FDOT2(rot2<RM, 7>(pdu), cx.w7, a1);                              \
        const float s = a0 + a1;                                              \
        const v2u sp = __builtin_amdgcn_permlane32_swap(                      \
            __float_as_uint(s), __float_as_uint(s), false, false);            \
        const float pre = __uint_as_float(sp.x) + __uint_as_float(sp.y);      \
        hn = pre * __builtin_amdgcn_rcpf(1.0f + __builtin_fabsf(pre));        \
        op[0] = hn;                                                           \
        op += ST;                                                             \
    } while (0)

    // ---- prologue: block 0 ----
    STAGE(0, 0);
    asm volatile("s_waitcnt vmcnt(0)" ::: "memory");
    COMPUTE_WX(0);
    f32x4 wq = *(const f32x4*)&wxT[0][cx.row][0];    // quad for steps 0-3
    float* op = cx.op;

    for (int tb = 0; tb < T_STEPS; tb += BLK) {
        const int cur = (tb >> 4) & 1, nxt = cur ^ 1;
        const bool more = (tb + BLK) < T_STEPS;
        if (more) STAGE(nxt, tb + BLK);       // unsinkable gl_lds

        const float* wrow_cur = &wxT[cur][cx.row][0];
        const float* wrow_nxt = &wxT[nxt][cx.row][0];

        // groups 0-2: prefetch next quad, then 4 steps on current quad.
        // ds_read_b128 issued 4 steps (~300cy) before its back-edge drain.
        f32x4 wqn;
#pragma clang loop unroll(disable)
        for (int gq = 1; gq <= 3; ++gq) {
            wqn = *(const f32x4*)(wrow_cur + 4 * gq);
            STEP(wq[0]); STEP(wq[1]); STEP(wq[2]); STEP(wq[3]);
            wq = wqn;
        }

        // next block's wx before the tail group.
        // queue: [4 prev-group stores][2 gl_lds][12 stores] -> vmcnt(12)
        if (more) {
            asm volatile("s_waitcnt vmcnt(12)" ::: "memory");
            COMPUTE_WX(nxt);
        }

        // tail group: steps 12-15 on q3; prefetch next block's quad 0
        // (LDS ops are wave-ordered: read after COMPUTE_WX's writes is safe;
        //  when !more the value is unused garbage, address in-bounds).
        wqn = *(const f32x4*)(wrow_nxt);
        STEP(wq[0]); STEP(wq[1]); STEP(wq[2]); STEP(wq[3]);
        wq = wqn;
    }

    cx.ofin[0] = hn;               // h_final (duplicates identical)
#undef STEP
#undef STAGE
#undef COMPUTE_WX
}

__global__ __launch_bounds__(64, 1)
void elman_fused(const float* __restrict__ x,
                 const float* __restrict__ h0,
                 const float* __restrict__ R,
                 const float* __restrict__ Wx,
                 const float* __restrict__ bias,
                 float* __restrict__ out)
{
    const int l = threadIdx.x & 63;
    const int c = l & 15;                // position within DPP row
    const int g = l >> 4;
    const int joff = (g == 1 || g == 2) ? 16 : 0;
    const int row  = (g & 1) ? 16 + c : c;
    const int h = blockIdx.x & (H_SZ - 1);
    const int b = blockIdx.x >> 6;

    // ---- convention probes (R8-proven) ----
    const int pr = __builtin_amdgcn_update_dpp(l, l, 0x121, 0xF, 0xF, false);
    const bool ror_minus = ((pr & 15) == ((c - 1) & 15));
    const v2u pp = __builtin_amdgcn_permlane16_swap((unsigned)l, (unsigned)l,
                                                    false, false);

    Ctx cx;
    cx.sel_x = (pp.x == (unsigned)(l ^ 16));
    cx.low32 = (l < 32);
    cx.row = row;

    // ---- wrapped-cover R weight pairs: start s_d = (c+2d)&15 ----
    {
        const float* Rrow = R + (h * HD + row) * HD + joff;
        f16x2 t[8];
#pragma unroll
        for (int d = 0; d < 8; ++d) {
            const int s = (c + 2 * d) & 15;
            t[d] = __builtin_amdgcn_cvt_pkrtz(Rrow[s], Rrow[(s + 1) & 15]);
        }
        cx.w0 = t[0]; cx.w1 = t[1]; cx.w2 = t[2]; cx.w3 = t[3];
        cx.w4 = t[4]; cx.w5 = t[5]; cx.w6 = t[6]; cx.w7 = t[7];
    }

    // ---- MFMA B fragments: B[k][n] = 0.5*Wx[h][n][k] f16 (R12-proven) ----
    {
        const int n  = l & 15;
        const int k0 = (l >> 4) * 8;
        const float4* wp0 = (const float4*)(Wx + (h * HD + n) * HD + k0);
        const float4* wp1 = (const float4*)(Wx + (h * HD + n + 16) * HD + k0);
        float4 u = wp0[0], v = wp0[1];
        cx.bf0.pcs[0] = __builtin_amdgcn_cvt_pkrtz(0.5f * u.x, 0.5f * u.y);
        cx.bf0.pcs[1] = __builtin_amdgcn_cvt_pkrtz(0.5f * u.z, 0.5f * u.w);
        cx.bf0.pcs[2] = __builtin_amdgcn_cvt_pkrtz(0.5f * v.x, 0.5f * v.y);
        cx.bf0.pcs[3] = __builtin_amdgcn_cvt_pkrtz(0.5f * v.z, 0.5f * v.w);
        u = wp1[0]; v = wp1[1];
        cx.bf1.pcs[0] = __builtin_amdgcn_cvt_pkrtz(0.5f * u.x, 0.5f * u.y);
        cx.bf1.pcs[1] = __builtin_amdgcn_cvt_pkrtz(0.5f * u.z, 0.5f * u.w);
        cx.bf1.pcs[2] = __builtin_amdgcn_cvt_pkrtz(0.5f * v.x, 0.5f * v.y);
        cx.bf1.pcs[3] = __builtin_amdgcn_cvt_pkrtz(0.5f * v.z, 0.5f * v.w);
        cx.bn0 = 0.5f * bias[h * HD + n];
        cx.bn1 = 0.5f * bias[h * HD + n + 16];
        cx.mr = (l >> 4) * 4;
        cx.nc = n;
    }

    // A-frag LDS word offsets (R10-proven)
    {
        const int J0 = (l >> 4) * 2, J1 = J0 + 1;
        cx.aw0 = 64 * (J0 & 3) + 4 * (l & 15) + 256 * (J0 >> 2);
        cx.aw1 = 64 * (J1 & 3) + 4 * (l & 15) + 256 * (J1 >> 2);
    }

    cx.gx0 = x + (long)(l & 15) * ST + (long)b * D_SZ + h * HD + (l >> 4) * 4;
    cx.gx1 = cx.gx0 + 16;
    cx.op  = out + (long)b * D_SZ + h * HD + row;
    cx.ofin = out + (long)T_STEPS * ST + (b * H_SZ + h) * HD + row;

    const float hn = h0[(b * H_SZ + h) * HD + row];

    __shared__ __align__(16) float xl[2][512];
    __shared__ __align__(16) float wxT[2][32][WPAD];

    if (ror_minus) run_scan<true>(cx, hn, xl, wxT);
    else           run_scan<false>(cx, hn, xl, wxT);
}

extern "C" void kernel_launch(void* const* d_in, const int* in_sizes, int n_in,
                              void* d_out, int out_size, void* d_ws, size_t ws_size,
                              hipStream_t stream) {
    const float* x    = (const float*)d_in[0];
    const float* h0   = (const float*)d_in[1];
    const float* R    = (const float*)d_in[2];
    const float* Wx   = (const float*)d_in[3];
    const float* bias = (const float*)d_in[4];
    float* out = (float*)d_out;

    elman_fused<<<dim3(B_SZ * H_SZ), dim3(64), 0, stream>>>(x, h0, R, Wx, bias, out);
}